// Round 11
// baseline (351.443 us; speedup 1.0000x reference)
//
#include <hip/hip_runtime.h>
#include <math.h>

#define BB 8
#define SS 1024
#define EE 768
#define HH 12
#define DD 64
#define MM (BB*SS)   // 8192
#define NBLK 192     // fused grid: 1 block/CU (96 KiB LDS), all co-resident

typedef __attribute__((ext_vector_type(8))) short short8;   // 8 bf16 = 4 VGPRs
typedef __attribute__((ext_vector_type(4))) short short4v;  // 8 B
typedef __attribute__((ext_vector_type(4))) float f32x4;
typedef __attribute__((ext_vector_type(4))) int int4v;

// round-to-nearest-even fp32 -> bf16 bits (finite inputs only)
static __device__ __forceinline__ short f2bf(float x) {
    unsigned u = __float_as_uint(x);
    u += 0x7fffu + ((u >> 16) & 1u);
    return (short)(u >> 16);
}
// packed fp32x2 -> bf16x2 (D.l = bf16(lo), D.h = bf16(hi))
static __device__ __forceinline__ int cvtpk_bf16(float lo, float hi) {
    int r;
    asm("v_cvt_pk_bf16_f32 %0, %1, %2" : "=v"(r) : "v"(lo), "v"(hi));
    return r;
}
static __device__ __forceinline__ short8 i4_to_s8(int4v v) {
    union { int4v i; short8 s; } u; u.i = v; return u.s;
}

// async global->LDS, 16B per lane; LDS dest = wave-uniform base + lane*16
static __device__ __forceinline__ void gload_lds16(const void* g, void* l) {
    __builtin_amdgcn_global_load_lds((__attribute__((address_space(1))) void*)g,
                                     (__attribute__((address_space(3))) void*)l,
                                     16, 0, 0);
}

#define BAR __builtin_amdgcn_s_barrier()
#define VMW(n) asm volatile("s_waitcnt vmcnt(" #n ")" ::: "memory")

// grid-wide barrier: counter zeroed per launch by captured hipMemsetAsync.
// All blocks co-resident (192 blocks, 1/CU via LDS, 256 CUs) -> spin is safe.
// __threadfence + agent-scope atomics per G16 (cross-XCD L2 non-coherence).
static __device__ __forceinline__ void gridbar(int* cnt, int idx) {
    __threadfence();
    __syncthreads();
    if (threadIdx.x == 0) {
        __hip_atomic_fetch_add(&cnt[idx], 1, __ATOMIC_ACQ_REL, __HIP_MEMORY_SCOPE_AGENT);
        while (__hip_atomic_load(&cnt[idx], __ATOMIC_ACQUIRE, __HIP_MEMORY_SCOPE_AGENT) < NBLK)
            __builtin_amdgcn_s_sleep(2);
    }
    __syncthreads();
}

// Q pre-scale: 1/sqrt(D) * log2(e)  (exp done as 2^x in attention)
#define QSCALE 0.1803368801111204f

// ---- qkv helpers (round-6 verified schedule) ----
#define STG1(Ld, Gbase, gr0, k0)                                              \
    do {                                                                      \
        const int r_ = tid >> 3;                                              \
        const int cs_ = ((tid & 7) ^ (r_ & 7)) << 3;                          \
        gload_lds16(&(Gbase)[(long)((gr0) + r_) * EE + (k0) + cs_],           \
                    (Ld) + w * 512);                                          \
    } while (0)

#define QKV_RDA(Ld, mb)                                                       \
    _Pragma("unroll") for (int t = 0; t < 4; ++t)                             \
        _Pragma("unroll") for (int ks = 0; ks < 2; ++ks)                      \
            af[t][ks] = *(const short8*)&(Ld)[(wr * 128 + ((mb) + t) * 16 + m) * 64 + \
                                              (((ks * 4 + quad) ^ (m & 7)) << 3)];

#define QKV_RDB(Ld)                                                           \
    _Pragma("unroll") for (int t = 0; t < 2; ++t)                             \
        _Pragma("unroll") for (int ks = 0; ks < 2; ++ks)                      \
            bf[t][ks] = *(const short8*)&(Ld)[(wc * 32 + t * 16 + m) * 64 +   \
                                              (((ks * 4 + quad) ^ (m & 7)) << 3)];

#define QKV_MF(mb)                                                            \
    __builtin_amdgcn_s_setprio(1);                                            \
    _Pragma("unroll") for (int mq = 0; mq < 4; ++mq)                          \
        _Pragma("unroll") for (int nq = 0; nq < 2; ++nq)                      \
            _Pragma("unroll") for (int ks = 0; ks < 2; ++ks)                  \
                acc[(mb) + mq][nq] = __builtin_amdgcn_mfma_f32_16x16x32_bf16( \
                    af[mq][ks], bf[nq][ks], acc[(mb) + mq][nq], 0, 0, 0);     \
    __builtin_amdgcn_s_setprio(0);

// ---- attn helpers: 8-wave supertile (256 q-rows share one K/V staging) ----
#define ATTN_STG8(Kdst, Vdst, k0)                                             \
    do {                                                                      \
        const int chunk = w * 64 + l;                                         \
        const int r = chunk >> 3;                                             \
        const int cs = ((chunk & 7) ^ (r & 7)) << 3;                          \
        gload_lds16(&Kg[(long)((k0) + r) * DD + cs], (Kdst) + w * 512);       \
        gload_lds16(&Vg[(long)r * SS + (k0) + cs], (Vdst) + w * 512);         \
    } while (0)

#define ATTN_COMPUTE(Kbuf, Vbuf)                                              \
    do {                                                                      \
        f32x4 sc[2][4];                                                       \
        __builtin_amdgcn_s_setprio(1);                                        \
        _Pragma("unroll") for (int nt = 0; nt < 4; ++nt) {                    \
            const short* kb = (Kbuf) + (nt * 16 + m) * 64;                    \
            short8 a0 = *(const short8*)&kb[(quad ^ (m & 7)) << 3];           \
            short8 a1 = *(const short8*)&kb[((4 + quad) ^ (m & 7)) << 3];     \
            _Pragma("unroll") for (int g = 0; g < 2; ++g) {                   \
                f32x4 a = (f32x4){0.f, 0.f, 0.f, 0.f};                        \
                a = __builtin_amdgcn_mfma_f32_16x16x32_bf16(a0, aq[g][0], a, 0, 0, 0); \
                a = __builtin_amdgcn_mfma_f32_16x16x32_bf16(a1, aq[g][1], a, 0, 0, 0); \
                sc[g][nt] = a;                                                \
            }                                                                 \
        }                                                                     \
        __builtin_amdgcn_s_setprio(0);                                        \
        _Pragma("unroll") for (int g = 0; g < 2; ++g)                         \
            _Pragma("unroll") for (int nt = 0; nt < 4; ++nt)                  \
                _Pragma("unroll") for (int r = 0; r < 4; ++r)                 \
                    sc[g][nt][r] = __builtin_amdgcn_exp2f(sc[g][nt][r]);      \
        short8 ap[2][2];                                                      \
        _Pragma("unroll") for (int g = 0; g < 2; ++g)                         \
            _Pragma("unroll") for (int hf = 0; hf < 2; ++hf) {                \
                int4v wv;                                                     \
                wv.x = cvtpk_bf16(sc[g][2 * hf + 0][0], sc[g][2 * hf + 0][1]); \
                wv.y = cvtpk_bf16(sc[g][2 * hf + 0][2], sc[g][2 * hf + 0][3]); \
                wv.z = cvtpk_bf16(sc[g][2 * hf + 1][0], sc[g][2 * hf + 1][1]); \
                wv.w = cvtpk_bf16(sc[g][2 * hf + 1][2], sc[g][2 * hf + 1][3]); \
                ap[g][hf] = i4_to_s8(wv);                                     \
            }                                                                 \
        __builtin_amdgcn_s_setprio(1);                                        \
        _Pragma("unroll") for (int g = 0; g < 2; ++g) {                       \
            lacc[g] = __builtin_amdgcn_mfma_f32_16x16x32_bf16(ap[g][0], ones, lacc[g], 0, 0, 0); \
            lacc[g] = __builtin_amdgcn_mfma_f32_16x16x32_bf16(ap[g][1], ones, lacc[g], 0, 0, 0); \
        }                                                                     \
        const int rsw = m & 7, hb = (quad & 1) * 4;                           \
        _Pragma("unroll") for (int dt = 0; dt < 4; ++dt) {                    \
            const short* vb = (Vbuf) + (dt * 16 + m) * 64;                    \
            short4v l0 = *(const short4v*)&vb[((((quad >> 1) + 0) ^ rsw) << 3) + hb]; \
            short4v h0 = *(const short4v*)&vb[((((quad >> 1) + 2) ^ rsw) << 3) + hb]; \
            short4v l1 = *(const short4v*)&vb[((((quad >> 1) + 4) ^ rsw) << 3) + hb]; \
            short4v h1 = *(const short4v*)&vb[((((quad >> 1) + 6) ^ rsw) << 3) + hb]; \
            short8 b0 = __builtin_shufflevector(l0, h0, 0, 1, 2, 3, 4, 5, 6, 7); \
            short8 b1 = __builtin_shufflevector(l1, h1, 0, 1, 2, 3, 4, 5, 6, 7); \
            _Pragma("unroll") for (int g = 0; g < 2; ++g) {                   \
                O[g][dt] = __builtin_amdgcn_mfma_f32_16x16x32_bf16(ap[g][0], b0, O[g][dt], 0, 0, 0); \
                O[g][dt] = __builtin_amdgcn_mfma_f32_16x16x32_bf16(ap[g][1], b1, O[g][dt], 0, 0, 0); \
            }                                                                 \
        }                                                                     \
        __builtin_amdgcn_s_setprio(0);                                        \
    } while (0)

// ---------------------------------------------------------------------------
// Fused single kernel: prep -> qkv -> attn -> proj with grid barriers.
// 192 blocks x 512 threads; every stage's tile count divides 192 exactly.
// ---------------------------------------------------------------------------
__global__ __launch_bounds__(512)
void fused(const float* __restrict__ X,
           const float* __restrict__ W0, const float* __restrict__ W1,
           const float* __restrict__ W2, const float* __restrict__ W3,
           const float* __restrict__ bq, const float* __restrict__ bk,
           const float* __restrict__ bv, const float* __restrict__ bo,
           short* __restrict__ Xb, short* __restrict__ Wt,
           short* __restrict__ Qb, short* __restrict__ Kb,
           short* __restrict__ Vb, short* __restrict__ Cb,
           float* __restrict__ out, int* bar) {
    __shared__ short SMEM[49152];            // 96 KiB -> 1 block/CU
    const int tid = threadIdx.x;
    const int w = tid >> 6;
    const int l = tid & 63;
    const int m = tid & 15, quad = (tid & 63) >> 4;
    const int xcd = blockIdx.x & 7;          // round-robin block->XCD
    const int slot = blockIdx.x >> 3;        // 0..23 within XCD

    // ================= stage 1: prep (W transpose-cast + X cast) ==========
    {
        short (*T)[72] = (short(*)[72])SMEM;
#pragma unroll 1
        for (int t = 0; t < 3; ++t) {        // 576 W-tiles / 192 blocks
            const int wid = blockIdx.x * 3 + t;
            const int z = wid / 144, r2 = wid % 144;
            const int i0 = (r2 / 12) * 64, j0 = (r2 % 12) * 64;
            const float* sp = (z == 0) ? W0 : (z == 1) ? W1 : (z == 2) ? W2 : W3;
            short* dp = Wt + (long)z * EE * EE;
#pragma unroll
            for (int rep = 0; rep < 2; ++rep) {
                const int r = (tid >> 4) + rep * 32;
                const int c = (tid & 15) * 4;
                float4 v = *(const float4*)&sp[(long)(i0 + r) * EE + j0 + c];
                T[c + 0][r] = f2bf(v.x);
                T[c + 1][r] = f2bf(v.y);
                T[c + 2][r] = f2bf(v.z);
                T[c + 3][r] = f2bf(v.w);
            }
            __syncthreads();
#pragma unroll
            for (int rep = 0; rep < 2; ++rep) {
                const int rr = (tid >> 4) + rep * 32;
                const int cc = (tid & 15) * 4;
                short4v o;
                o.x = T[rr][cc + 0]; o.y = T[rr][cc + 1];
                o.z = T[rr][cc + 2]; o.w = T[rr][cc + 3];
                *(short4v*)&dp[(long)(j0 + rr) * EE + i0 + cc] = o;
            }
            __syncthreads();
        }
        const long base = (long)blockIdx.x * 512 + tid;
#pragma unroll 4
        for (int it2 = 0; it2 < 16; ++it2) { // 1.57M float4 / (192*512)
            const long q = (base + (long)it2 * (NBLK * 512)) * 4;
            float4 v = *(const float4*)&X[q];
            short4v o;
            o.x = f2bf(v.x); o.y = f2bf(v.y); o.z = f2bf(v.z); o.w = f2bf(v.w);
            *(short4v*)&Xb[q] = o;
        }
    }
    gridbar(bar, 0);

    // ================= stage 2: qkv (round-6 schedule, 3 rounds) ==========
    {
        short* const Ae = SMEM;
        short* const Ao = SMEM + 16384;
        short* const Be = SMEM + 32768;
        short* const Bo = SMEM + 40960;
        const int wr = w >> 2, wc = w & 3;
#pragma unroll 1
        for (int rnd = 0; rnd < 3; ++rnd) {  // 576 tiles / 192 = 3 exact
            const int id = xcd * 72 + rnd * 24 + slot;
            const int lcl = id % 72;
            const int rt = xcd * 4 + (lcl & 3);
            const int ct = lcl >> 2;
            const int row0 = rt * 256;
            const int wsel = ct / 6;
            const int col0w = (ct % 6) * 128;
            const short* Wsel = Wt + (long)wsel * EE * EE;
            const float* bias = (wsel == 0) ? bq : (wsel == 1) ? bk : bv;

            f32x4 acc[8][2];
#pragma unroll
            for (int i = 0; i < 8; ++i)
#pragma unroll
                for (int j = 0; j < 2; ++j) acc[i][j] = (f32x4){0.f, 0.f, 0.f, 0.f};

            STG1(Ae + 0,     Xb,   row0 + 0,    0);
            STG1(Ae + 8192,  Xb,   row0 + 128,  0);
            STG1(Be + 0,     Wsel, col0w + 0,   0);
            STG1(Be + 4096,  Wsel, col0w + 64,  0);
            STG1(Ae + 4096,  Xb,   row0 + 64,   0);
            STG1(Ae + 12288, Xb,   row0 + 192,  0);
            STG1(Bo + 0,     Wsel, col0w + 0,   64);
            STG1(Bo + 4096,  Wsel, col0w + 64,  64);
            STG1(Ao + 0,     Xb,   row0 + 0,    64);
            STG1(Ao + 8192,  Xb,   row0 + 128,  64);
            VMW(6);
            BAR;

#pragma unroll 1
            for (int it = 0; it < 6; ++it) {
                const int kO1 = (2 * it + 1) * 64;
                const int t2 = 2 * it + 2, t3 = 2 * it + 3;
                const int kE2 = (t2 < 12 ? t2 : 11) * 64;
                const int kO3 = (t3 < 12 ? t3 : 11) * 64;
                short8 af[4][2], bf[2][2];
                QKV_RDA(Ae, 0);
                QKV_RDB(Be);
                STG1(Ao + 4096,  Xb, row0 + 64,  kO1);
                STG1(Ao + 12288, Xb, row0 + 192, kO1);
                BAR;
                QKV_MF(0);
                VMW(6);
                BAR;
                QKV_RDA(Ae, 4);
                STG1(Be + 0,     Wsel, col0w + 0,  kE2);
                STG1(Be + 4096,  Wsel, col0w + 64, kE2);
                STG1(Ae + 0,     Xb,   row0 + 0,   kE2);
                STG1(Ae + 8192,  Xb,   row0 + 128, kE2);
                BAR;
                QKV_MF(4);
                VMW(6);
                BAR;
                QKV_RDA(Ao, 0);
                QKV_RDB(Bo);
                STG1(Ae + 4096,  Xb, row0 + 64,  kE2);
                STG1(Ae + 12288, Xb, row0 + 192, kE2);
                BAR;
                QKV_MF(0);
                VMW(6);
                BAR;
                QKV_RDA(Ao, 4);
                STG1(Bo + 0,     Wsel, col0w + 0,  kO3);
                STG1(Bo + 4096,  Wsel, col0w + 64, kO3);
                STG1(Ao + 0,     Xb,   row0 + 0,   kO3);
                STG1(Ao + 8192,  Xb,   row0 + 128, kO3);
                BAR;
                QKV_MF(4);
                VMW(6);
                BAR;
            }

            VMW(0);
            __syncthreads();
            const int b = row0 >> 10, s0 = row0 & 1023;
            short* EP = SMEM;
            if (wsel < 2) {
                const float scale = (wsel == 0) ? QSCALE : 1.0f;
                short* QK = (wsel == 0) ? Qb : Kb;
#pragma unroll
                for (int nt = 0; nt < 2; ++nt) {
                    const float bvv = bias[col0w + wc * 32 + nt * 16 + m];
#pragma unroll
                    for (int mt = 0; mt < 8; ++mt)
#pragma unroll
                        for (int r = 0; r < 4; ++r)
                            EP[(wr * 128 + mt * 16 + quad * 4 + r) * 136 + wc * 32 + nt * 16 + m] =
                                f2bf((acc[mt][nt][r] + bvv) * scale);
                }
                __syncthreads();
#pragma unroll
                for (int rep = 0; rep < 8; ++rep) {
                    const int chunk = tid + rep * 512;
                    const int row = chunk >> 4;
                    const int cc = (chunk & 15) * 8;
                    const int colg = col0w + cc;
                    const int h = colg >> 6, d = colg & 63;
                    short8 v = *(const short8*)&EP[row * 136 + cc];
                    *(short8*)&QK[((long)(b * HH + h) * SS + s0 + row) * DD + d] = v;
                }
            } else {
#pragma unroll
                for (int nt = 0; nt < 2; ++nt) {
                    const float bvv = bias[col0w + wc * 32 + nt * 16 + m];
#pragma unroll
                    for (int mt = 0; mt < 8; ++mt) {
                        short4v o;
                        o.x = f2bf(acc[mt][nt][0] + bvv);
                        o.y = f2bf(acc[mt][nt][1] + bvv);
                        o.z = f2bf(acc[mt][nt][2] + bvv);
                        o.w = f2bf(acc[mt][nt][3] + bvv);
                        *(short4v*)&EP[(wc * 32 + nt * 16 + m) * 264 + wr * 128 + mt * 16 + quad * 4] = o;
                    }
                }
                __syncthreads();
#pragma unroll
                for (int rep = 0; rep < 8; ++rep) {
                    const int chunk = tid + rep * 512;
                    const int col = chunk >> 5;
                    const int sc8 = (chunk & 31) * 8;
                    const int colg = col0w + col;
                    const int h = colg >> 6, d = colg & 63;
                    short8 v = *(const short8*)&EP[col * 264 + sc8];
                    *(short8*)&Vb[((long)(b * HH + h) * DD + d) * SS + s0 + sc8] = v;
                }
            }
            __syncthreads();   // EP/LDS safe before next round's prologue
        }
    }
    gridbar(bar, 1);

    // ================= stage 3: attn (8-wave supertile, 2 rounds) =========
    {
        short* const K0l = SMEM;
        short* const K1l = SMEM + 4096;
        short* const V0l = SMEM + 8192;
        short* const V1l = SMEM + 12288;
#pragma unroll 1
        for (int rnd = 0; rnd < 2; ++rnd) {  // 384 supertiles / 192 = 2 exact
            const int vid = xcd * 48 + rnd * 24 + slot;
            const int bh = vid >> 2, st = vid & 3;   // XCD k: bh in [12k,12k+12)
            const int b = bh / HH, h = bh % HH;
            const int q0 = st * 256;

            const short* Qg = Qb + (long)bh * SS * DD;
            const short* Kg = Kb + (long)bh * SS * DD;
            const short* Vg = Vb + (long)bh * DD * SS;

            short8 aq[2][2];
#pragma unroll
            for (int g = 0; g < 2; ++g) {
                const int row = q0 + w * 32 + g * 16 + m;
                aq[g][0] = *(const short8*)(Qg + (long)row * DD + quad * 8);
                aq[g][1] = *(const short8*)(Qg + (long)row * DD + 32 + quad * 8);
            }
            short8 ones;
#pragma unroll
            for (int i = 0; i < 8; ++i) ones[i] = (short)0x3F80;

            f32x4 O[2][4], lacc[2];
#pragma unroll
            for (int g = 0; g < 2; ++g) {
                lacc[g] = (f32x4){0.f, 0.f, 0.f, 0.f};
#pragma unroll
                for (int dt = 0; dt < 4; ++dt) O[g][dt] = (f32x4){0.f, 0.f, 0.f, 0.f};
            }

            ATTN_STG8(K0l, V0l, 0);
            __syncthreads();
#pragma unroll 1
            for (int kt2 = 0; kt2 < 8; ++kt2) {
                const int k0 = kt2 * 128;
                ATTN_STG8(K1l, V1l, k0 + 64);
                ATTN_COMPUTE(K0l, V0l);
                __syncthreads();
                if (kt2 < 7) ATTN_STG8(K0l, V0l, k0 + 128);
                ATTN_COMPUTE(K1l, V1l);
                __syncthreads();
            }
#pragma unroll
            for (int g = 0; g < 2; ++g)
#pragma unroll
                for (int r = 0; r < 4; ++r) {
                    const float inv = 1.0f / lacc[g][r];
                    const int qo = q0 + w * 32 + g * 16 + quad * 4 + r;
                    short* orow = Cb + ((long)(b * SS + qo)) * EE + h * DD;
#pragma unroll
                    for (int dt = 0; dt < 4; ++dt)
                        orow[dt * 16 + m] = f2bf(O[g][dt][r] * inv);
                }
        }
    }
    gridbar(bar, 2);

    // ================= stage 4: proj (128x256 tile, 1 round) ==============
    {
        short* const Al = SMEM;              // 128x64 bf16 (16 KiB)
        short* const Bl = SMEM + 8192;       // 256x64 bf16 (32 KiB)
        const short* WoT = Wt + (long)3 * EE * EE;
        const int rt = xcd * 8 + (slot & 7); // 0..63
        const int ct = slot >> 3;            // 0..2
        const int row0 = rt * 128;
        const int col0 = ct * 256;
        const int rm2 = (w >> 2) * 64, cn2 = (w & 3) * 64;

        f32x4 acc[4][4];
#pragma unroll
        for (int i = 0; i < 4; ++i)
#pragma unroll
            for (int j = 0; j < 4; ++j) acc[i][j] = (f32x4){0.f, 0.f, 0.f, 0.f};

#pragma unroll 1
        for (int k0 = 0; k0 < EE; k0 += 64) {
            __syncthreads();
#pragma unroll
            for (int j = 0; j < 2; ++j) {    // A: 1024 chunks
                const int c = tid + j * 512;
                const int r = c >> 3;
                const int cs = ((c & 7) ^ (r & 7)) << 3;
                gload_lds16(&Cb[(long)(row0 + r) * EE + k0 + cs],
                            Al + (j * 512 + w * 64) * 8);
            }
#pragma unroll
            for (int j = 0; j < 4; ++j) {    // B: 2048 chunks
                const int c = tid + j * 512;
                const int r = c >> 3;
                const int cs = ((c & 7) ^ (r & 7)) << 3;
                gload_lds16(&WoT[(long)(col0 + r) * EE + k0 + cs],
                            Bl + (j * 512 + w * 64) * 8);
            }
            __syncthreads();
#pragma unroll
            for (int ks = 0; ks < 2; ++ks) {
                short8 af[4], bf[4];
#pragma unroll
                for (int t = 0; t < 4; ++t)
                    af[t] = *(const short8*)&Al[(rm2 + t * 16 + m) * 64 +
                                                (((ks * 4 + quad) ^ (m & 7)) << 3)];
#pragma unroll
                for (int t = 0; t < 4; ++t)
                    bf[t] = *(const short8*)&Bl[(cn2 + t * 16 + m) * 64 +
                                                (((ks * 4 + quad) ^ (m & 7)) << 3)];
#pragma unroll
                for (int mt = 0; mt < 4; ++mt)
#pragma unroll
                    for (int nt = 0; nt < 4; ++nt)
                        acc[mt][nt] = __builtin_amdgcn_mfma_f32_16x16x32_bf16(
                            af[mt], bf[nt], acc[mt][nt], 0, 0, 0);
            }
        }
#pragma unroll
        for (int nt = 0; nt < 4; ++nt) {
            const int colg = col0 + cn2 + nt * 16 + m;
            const float bvv = bo[colg];
#pragma unroll
            for (int mt = 0; mt < 4; ++mt)
#pragma unroll
                for (int r = 0; r < 4; ++r) {
                    const int srow = row0 + rm2 + mt * 16 + quad * 4 + r;
                    out[(long)srow * EE + colg] = acc[mt][nt][r] + bvv;
                }
        }
    }
}

// ---------------------------------------------------------------------------
extern "C" void kernel_launch(void* const* d_in, const int* in_sizes, int n_in,
                              void* d_out, int out_size, void* d_ws, size_t ws_size,
                              hipStream_t stream) {
    const float* X  = (const float*)d_in[0];
    const float* Wq = (const float*)d_in[1];
    const float* bq = (const float*)d_in[2];
    const float* Wk = (const float*)d_in[3];
    const float* bk = (const float*)d_in[4];
    const float* Wv = (const float*)d_in[5];
    const float* bv = (const float*)d_in[6];
    const float* Wo = (const float*)d_in[7];
    const float* bo = (const float*)d_in[8];

    const long SEG = (long)BB * HH * SS * DD;     // 6,291,456 elements
    const long WSEG = (long)EE * EE;              // 589,824
    short* Xb = (short*)d_ws;                     // [M][E] bf16
    short* Wt = Xb + SEG;                         // [4][E][E] bf16, N-major
    short* Qb = Wt + 4 * WSEG;                    // [B,H,S,D] bf16, pre-scaled
    short* Kb = Qb + SEG;                         // [B,H,S,D] bf16
    short* Vb = Kb + SEG;                         // [B,H,D,S] bf16
    short* Cb = Vb + SEG;                         // [M][E] bf16 concat
    int*   bar = (int*)(Cb + SEG);                // 3 grid-barrier counters

    hipMemsetAsync(bar, 0, 64, stream);
    fused<<<dim3(NBLK), 512, 0, stream>>>(X, Wq, Wk, Wv, Wo, bq, bk, bv, bo,
                                          Xb, Wt, Qb, Kb, Vb, Cb,
                                          (float*)d_out, bar);
}

// Round 12
// 194.749 us; speedup vs baseline: 1.8046x; 1.8046x over previous
//
#include <hip/hip_runtime.h>
#include <math.h>

#define BB 8
#define SS 1024
#define EE 768
#define HH 12
#define DD 64
#define MM (BB*SS)   // 8192

typedef __attribute__((ext_vector_type(8))) short short8;   // 8 bf16 = 4 VGPRs
typedef __attribute__((ext_vector_type(4))) short short4v;  // 8 B
typedef __attribute__((ext_vector_type(4))) float f32x4;
typedef __attribute__((ext_vector_type(4))) int int4v;

// round-to-nearest-even fp32 -> bf16 bits (finite inputs only)
static __device__ __forceinline__ short f2bf(float x) {
    unsigned u = __float_as_uint(x);
    u += 0x7fffu + ((u >> 16) & 1u);
    return (short)(u >> 16);
}
// packed fp32x2 -> bf16x2 (D.l = bf16(lo), D.h = bf16(hi))
static __device__ __forceinline__ int cvtpk_bf16(float lo, float hi) {
    int r;
    asm("v_cvt_pk_bf16_f32 %0, %1, %2" : "=v"(r) : "v"(lo), "v"(hi));
    return r;
}
static __device__ __forceinline__ short8 i4_to_s8(int4v v) {
    union { int4v i; short8 s; } u; u.i = v; return u.s;
}

// async global->LDS, 16B per lane; LDS dest = wave-uniform base + lane*16
static __device__ __forceinline__ void gload_lds16(const void* g, void* l) {
    __builtin_amdgcn_global_load_lds((__attribute__((address_space(1))) void*)g,
                                     (__attribute__((address_space(3))) void*)l,
                                     16, 0, 0);
}

#define BAR __builtin_amdgcn_s_barrier()
#define VMW(n) asm volatile("s_waitcnt vmcnt(" #n ")" ::: "memory")

// ---------------------------------------------------------------------------
// prep: fused cast_x (blocks 0..6143) + wcast_t (blocks 6144..6719).
// ---------------------------------------------------------------------------
__global__ __launch_bounds__(256)
void prep(const float* __restrict__ X, short* __restrict__ Xb,
          const float* __restrict__ W0, const float* __restrict__ W1,
          const float* __restrict__ W2, const float* __restrict__ W3,
          short* __restrict__ Wt) {
    const int tid = threadIdx.x;
    if (blockIdx.x < 6144) {
        const long i = ((long)blockIdx.x * 256 + tid) * 4;
        float4 v = *(const float4*)&X[i];
        short4v o;
        o.x = f2bf(v.x); o.y = f2bf(v.y); o.z = f2bf(v.z); o.w = f2bf(v.w);
        *(short4v*)&Xb[i] = o;
        return;
    }
    __shared__ short T[64][72];
    const int id = blockIdx.x - 6144;            // 0..575
    const int z  = id / 144;
    const int r2 = id % 144;
    const int i0 = (r2 / 12) * 64;
    const int j0 = (r2 % 12) * 64;
    const float* sp = (z == 0) ? W0 : (z == 1) ? W1 : (z == 2) ? W2 : W3;
    short* dp = Wt + (long)z * EE * EE;
#pragma unroll
    for (int rep = 0; rep < 4; ++rep) {
        const int r = (tid >> 4) + rep * 16;
        const int c = (tid & 15) * 4;
        float4 v = *(const float4*)&sp[(long)(i0 + r) * EE + j0 + c];
        T[c + 0][r] = f2bf(v.x);
        T[c + 1][r] = f2bf(v.y);
        T[c + 2][r] = f2bf(v.z);
        T[c + 3][r] = f2bf(v.w);
    }
    __syncthreads();
#pragma unroll
    for (int rep = 0; rep < 4; ++rep) {
        const int rr = (tid >> 4) + rep * 16;
        const int cc = (tid & 15) * 4;
        short4v o;
        o.x = T[rr][cc + 0]; o.y = T[rr][cc + 1];
        o.z = T[rr][cc + 2]; o.w = T[rr][cc + 3];
        *(short4v*)&dp[(long)(j0 + rr) * EE + i0 + cc] = o;
    }
}

// ---------------------------------------------------------------------------
// bf16 MFMA GEMM core (m97 structure) — still used by gemm_proj.
// ---------------------------------------------------------------------------
#define GEMM_CORE(Abase, Bbase, row0, col0)                                     \
    f32x4 acc[4][4];                                                            \
    _Pragma("unroll") for (int i = 0; i < 4; ++i)                               \
        _Pragma("unroll") for (int j = 0; j < 4; ++j)                           \
            acc[i][j] = (f32x4){0.f, 0.f, 0.f, 0.f};                            \
    const int rm = (w & 1) * 64, cn = (w >> 1) * 64;                            \
    for (int k0 = 0; k0 < EE; k0 += 64) {                                       \
        __syncthreads();                                                        \
        _Pragma("unroll") for (int i = 0; i < 4; ++i) {                         \
            const int chunk = w * 256 + i * 64 + lane;                          \
            const int r = chunk >> 3;                                          \
            const int cs = (((chunk & 7) ^ (r & 7)) << 3);                      \
            short* ldsA = Al + (w * 256 + i * 64) * 8;                          \
            short* ldsB = Bl + (w * 256 + i * 64) * 8;                          \
            gload_lds16(&Abase[(long)(row0 + r) * EE + k0 + cs], ldsA);         \
            gload_lds16(&Bbase[(long)(col0 + r) * EE + k0 + cs], ldsB);         \
        }                                                                       \
        __syncthreads();                                                        \
        _Pragma("unroll") for (int ks = 0; ks < 2; ++ks) {                      \
            short8 af[4], bf[4];                                                \
            _Pragma("unroll") for (int t = 0; t < 4; ++t)                       \
                af[t] = *(const short8*)&Al[(rm + t * 16 + m) * 64 +            \
                                            (((ks * 4 + quad) ^ (m & 7)) << 3)]; \
            _Pragma("unroll") for (int t = 0; t < 4; ++t)                       \
                bf[t] = *(const short8*)&Bl[(cn + t * 16 + m) * 64 +            \
                                            (((ks * 4 + quad) ^ (m & 7)) << 3)]; \
            _Pragma("unroll") for (int mt = 0; mt < 4; ++mt)                    \
                _Pragma("unroll") for (int nt = 0; nt < 4; ++nt)                \
                    acc[mt][nt] = __builtin_amdgcn_mfma_f32_16x16x32_bf16(      \
                        af[mt], bf[nt], acc[mt][nt], 0, 0, 0);                  \
        }                                                                       \
    }

// Q pre-scale: 1/sqrt(D) * log2(e)  (exp done as 2^x in attention)
#define QSCALE 0.1803368801111204f

// ---------------------------------------------------------------------------
// Fused QKV — 256x128 tile, BK=64, 512 thr / 8 waves (2M x 4N), per-wave
// C = 128x32 = acc[8][2]. 4-phase counted-vmcnt pipeline (T2+T4+T5).
// Grid 32x18 = 576 blocks. LDS 96 KiB, dual-buffered A (Ae/Ao) and B (Be/Bo),
// VMW(6) per phase = 6 loads always in flight.
// ROUND-6 VERIFIED VERSION (48.0 us). Occupancy-reduction variants (80 KiB
// single-B: 51.7; 64 KiB ring: 61.6) and the 192-block grid-barrier
// mega-fusion (283 us) were all slower — prefetch depth + independent
// multi-block TLP, not blocks/CU or fewer launches, is what this workload
// pays for. Do not restructure.
// ---------------------------------------------------------------------------
#define STG1(Ld, Gbase, gr0, k0)                                              \
    do {                                                                      \
        const int r_ = tid >> 3;                                              \
        const int cs_ = ((tid & 7) ^ (r_ & 7)) << 3;                          \
        gload_lds16(&(Gbase)[(long)((gr0) + r_) * EE + (k0) + cs_],           \
                    (Ld) + w * 512);                                          \
    } while (0)

#define QKV_RDA(Ld, mb)                                                       \
    _Pragma("unroll") for (int t = 0; t < 4; ++t)                             \
        _Pragma("unroll") for (int ks = 0; ks < 2; ++ks)                      \
            af[t][ks] = *(const short8*)&(Ld)[(wr * 128 + ((mb) + t) * 16 + m) * 64 + \
                                              (((ks * 4 + quad) ^ (m & 7)) << 3)];

#define QKV_RDB(Ld)                                                           \
    _Pragma("unroll") for (int t = 0; t < 2; ++t)                             \
        _Pragma("unroll") for (int ks = 0; ks < 2; ++ks)                      \
            bf[t][ks] = *(const short8*)&(Ld)[(wc * 32 + t * 16 + m) * 64 +   \
                                              (((ks * 4 + quad) ^ (m & 7)) << 3)];

#define QKV_MF(mb)                                                            \
    __builtin_amdgcn_s_setprio(1);                                            \
    _Pragma("unroll") for (int mq = 0; mq < 4; ++mq)                          \
        _Pragma("unroll") for (int nq = 0; nq < 2; ++nq)                      \
            _Pragma("unroll") for (int ks = 0; ks < 2; ++ks)                  \
                acc[(mb) + mq][nq] = __builtin_amdgcn_mfma_f32_16x16x32_bf16( \
                    af[mq][ks], bf[nq][ks], acc[(mb) + mq][nq], 0, 0, 0);     \
    __builtin_amdgcn_s_setprio(0);

__global__ __launch_bounds__(512, 2)
void gemm_qkv(const short* __restrict__ Xb, const short* __restrict__ Wt,
              const float* __restrict__ bq, const float* __restrict__ bk,
              const float* __restrict__ bv,
              short* __restrict__ Qb, short* __restrict__ Kb,
              short* __restrict__ Vb) {
    __shared__ short SMEM[49152];            // 96 KiB
    short* const Ae = SMEM;                  // 256x64 bf16 even-tile A
    short* const Ao = SMEM + 16384;          // odd-tile A
    short* const Be = SMEM + 32768;          // 128x64 bf16 even-tile B
    short* const Bo = SMEM + 40960;          // odd-tile B

    const int tid = threadIdx.x;
    const int w = tid >> 6;
    const int m = tid & 15, quad = (tid & 63) >> 4;
    const int wr = w >> 2, wc = w & 3;       // 2M x 4N wave grid

    const int flat = blockIdx.x + 18 * blockIdx.y;      // 0..575
    const int id   = (flat & 7) * 72 + (flat >> 3);
    const int lcl  = id % 72;
    const int rt   = (id / 72) * 4 + (lcl & 3);         // 0..31
    const int ct   = lcl >> 2;                          // 0..17
    const int row0 = rt * 256;
    const int wsel = ct / 6;
    const int col0w = (ct % 6) * 128;
    const short* Wsel = Wt + (long)wsel * EE * EE;
    const float* bias = (wsel == 0) ? bq : (wsel == 1) ? bk : bv;

    f32x4 acc[8][2];
#pragma unroll
    for (int i = 0; i < 8; ++i)
#pragma unroll
        for (int j = 0; j < 2; ++j) acc[i][j] = (f32x4){0.f, 0.f, 0.f, 0.f};

    // ---- prologue: chain-compatible order, 10 loads ----
    STG1(Ae + 0,     Xb,   row0 + 0,    0);
    STG1(Ae + 8192,  Xb,   row0 + 128,  0);
    STG1(Be + 0,     Wsel, col0w + 0,   0);
    STG1(Be + 4096,  Wsel, col0w + 64,  0);
    STG1(Ae + 4096,  Xb,   row0 + 64,   0);
    STG1(Ae + 12288, Xb,   row0 + 192,  0);
    STG1(Bo + 0,     Wsel, col0w + 0,   64);
    STG1(Bo + 4096,  Wsel, col0w + 64,  64);
    STG1(Ao + 0,     Xb,   row0 + 0,    64);
    STG1(Ao + 8192,  Xb,   row0 + 128,  64);
    VMW(6);
    BAR;

#pragma unroll 1
    for (int it = 0; it < 6; ++it) {
        const int kO1 = (2 * it + 1) * 64;              // <= 704, always valid
        const int t2 = 2 * it + 2, t3 = 2 * it + 3;
        const int kE2 = (t2 < 12 ? t2 : 11) * 64;       // clamp: hot re-read
        const int kO3 = (t3 < 12 ? t3 : 11) * 64;
        short8 af[4][2], bf[2][2];
        // -- phase 1: even tile, M-half 0 --
        QKV_RDA(Ae, 0);
        QKV_RDB(Be);
        STG1(Ao + 4096,  Xb, row0 + 64,  kO1);          // Ao.q13[t+1]
        STG1(Ao + 12288, Xb, row0 + 192, kO1);
        BAR;
        QKV_MF(0);
        VMW(6);
        BAR;
        // -- phase 2: even tile, M-half 1 (B-frags live in regs) --
        QKV_RDA(Ae, 4);
        STG1(Be + 0,     Wsel, col0w + 0,  kE2);        // Be[t+2]
        STG1(Be + 4096,  Wsel, col0w + 64, kE2);
        STG1(Ae + 0,     Xb,   row0 + 0,   kE2);        // Ae.q02[t+2]
        STG1(Ae + 8192,  Xb,   row0 + 128, kE2);
        BAR;
        QKV_MF(4);
        VMW(6);
        BAR;
        // -- phase 3: odd tile, M-half 0 --
        QKV_RDA(Ao, 0);
        QKV_RDB(Bo);
        STG1(Ae + 4096,  Xb, row0 + 64,  kE2);          // Ae.q13[t+2]
        STG1(Ae + 12288, Xb, row0 + 192, kE2);
        BAR;
        QKV_MF(0);
        VMW(6);
        BAR;
        // -- phase 4: odd tile, M-half 1 --
        QKV_RDA(Ao, 4);
        STG1(Bo + 0,     Wsel, col0w + 0,  kO3);        // Bo[t+3]
        STG1(Bo + 4096,  Wsel, col0w + 64, kO3);
        STG1(Ao + 0,     Xb,   row0 + 0,   kO3);        // Ao.q02[t+3]
        STG1(Ao + 8192,  Xb,   row0 + 128, kO3);
        BAR;
        QKV_MF(4);
        VMW(6);
        BAR;
    }

    // ---- epilogue ----
    VMW(0);
    __syncthreads();
    const int b = row0 >> 10, s0 = row0 & 1023;
    short* EP = SMEM;

    if (wsel < 2) {
        // Q/K -> [B,H,S,D]; EP as [256][136]
        const float scale = (wsel == 0) ? QSCALE : 1.0f;
        short* QK = (wsel == 0) ? Qb : Kb;
#pragma unroll
        for (int nt = 0; nt < 2; ++nt) {
            const float bvv = bias[col0w + wc * 32 + nt * 16 + m];
#pragma unroll
            for (int mt = 0; mt < 8; ++mt)
#pragma unroll
                for (int r = 0; r < 4; ++r)
                    EP[(wr * 128 + mt * 16 + quad * 4 + r) * 136 + wc * 32 + nt * 16 + m] =
                        f2bf((acc[mt][nt][r] + bvv) * scale);
        }
        __syncthreads();
#pragma unroll
        for (int rep = 0; rep < 8; ++rep) {
            const int chunk = tid + rep * 512;      // 0..4095
            const int row = chunk >> 4;             // 0..255
            const int cc = (chunk & 15) * 8;        // 0..120
            const int colg = col0w + cc;
            const int h = colg >> 6, d = colg & 63;
            short8 v = *(const short8*)&EP[row * 136 + cc];
            *(short8*)&QK[((long)(b * HH + h) * SS + s0 + row) * DD + d] = v;
        }
    } else {
        // V -> [B,H,D,S]; EP transposed as [128][264]
#pragma unroll
        for (int nt = 0; nt < 2; ++nt) {
            const float bvv = bias[col0w + wc * 32 + nt * 16 + m];
#pragma unroll
            for (int mt = 0; mt < 8; ++mt) {
                short4v o;
                o.x = f2bf(acc[mt][nt][0] + bvv);
                o.y = f2bf(acc[mt][nt][1] + bvv);
                o.z = f2bf(acc[mt][nt][2] + bvv);
                o.w = f2bf(acc[mt][nt][3] + bvv);
                *(short4v*)&EP[(wc * 32 + nt * 16 + m) * 264 + wr * 128 + mt * 16 + quad * 4] = o;
            }
        }
        __syncthreads();
#pragma unroll
        for (int rep = 0; rep < 8; ++rep) {
            const int chunk = tid + rep * 512;      // 0..4095
            const int col = chunk >> 5;             // 0..127
            const int sc8 = (chunk & 31) * 8;       // 0..248
            const int colg = col0w + col;
            const int h = colg >> 6, d = colg & 63;
            short8 v = *(const short8*)&EP[col * 264 + sc8];
            *(short8*)&Vb[((long)(b * HH + h) * DD + d) * SS + s0 + sc8] = v;
        }
    }
}

// Output projection: Cb bf16 [M][E] @ WoT + bo -> fp32 d_out. 384 blocks,
// XCD chunk = 8 row-tiles x 6 cols.
__global__ __launch_bounds__(256)
void gemm_proj(const short* __restrict__ Cb, const short* __restrict__ WoT,
               const float* __restrict__ bo, float* __restrict__ out) {
    __shared__ short Al[128 * 64];
    __shared__ short Bl[128 * 64];
    const int tid = threadIdx.x, w = tid >> 6, lane = tid & 63;
    const int m = lane & 15, quad = lane >> 4;

    const int flat = blockIdx.x + 6 * blockIdx.y;       // 0..383
    const int id   = (flat & 7) * 48 + (flat >> 3);
    const int xcd  = id / 48;
    const int lcl  = id % 48;
    const int row0 = (xcd * 8 + (lcl & 7)) * 128;
    const int col0 = (lcl >> 3) * 128;

    GEMM_CORE(Cb, WoT, row0, col0)

#pragma unroll
    for (int nt = 0; nt < 4; ++nt) {
        const int colg = col0 + cn + nt * 16 + m;
        const float bvv = bo[colg];
#pragma unroll
        for (int mt = 0; mt < 4; ++mt)
#pragma unroll
            for (int r = 0; r < 4; ++r) {
                const int srow = row0 + rm + mt * 16 + quad * 4 + r;
                out[(long)srow * EE + colg] = acc[mt][nt][r] + bvv;
            }
    }
}

// ---------------------------------------------------------------------------
// Flash attention, bf16 MFMA 16x16x32. SWAPPED QK^T + in-register P.
// (round-6 version, verified)
// ---------------------------------------------------------------------------
#define ATTN_STAGE(Kdst, Vdst, k0)                                            \
    do {                                                                      \
        _Pragma("unroll") for (int i = 0; i < 2; ++i) {                       \
            const int chunk = w * 128 + i * 64 + l;                           \
            const int r = chunk >> 3;                                         \
            const int cs = ((chunk & 7) ^ (r & 7)) << 3;                      \
            gload_lds16(&Kg[(long)((k0) + r) * DD + cs],                      \
                        (Kdst) + (w * 128 + i * 64) * 8);                     \
            gload_lds16(&Vg[(long)r * SS + (k0) + cs],                        \
                        (Vdst) + (w * 128 + i * 64) * 8);                     \
        }                                                                     \
    } while (0)

#define ATTN_COMPUTE(Kbuf, Vbuf)                                              \
    do {                                                                      \
        f32x4 sc[2][4];                                                       \
        __builtin_amdgcn_s_setprio(1);                                        \
        _Pragma("unroll") for (int nt = 0; nt < 4; ++nt) {                    \
            const short* kb = (Kbuf) + (nt * 16 + m) * 64;                    \
            short8 a0 = *(const short8*)&kb[(quad ^ (m & 7)) << 3];           \
            short8 a1 = *(const short8*)&kb[((4 + quad) ^ (m & 7)) << 3];     \
            _Pragma("unroll") for (int g = 0; g < 2; ++g) {                   \
                f32x4 a = (f32x4){0.f, 0.f, 0.f, 0.f};                        \
                a = __builtin_amdgcn_mfma_f32_16x16x32_bf16(a0, aq[g][0], a, 0, 0, 0); \
                a = __builtin_amdgcn_mfma_f32_16x16x32_bf16(a1, aq[g][1], a, 0, 0, 0); \
                sc[g][nt] = a;                                                \
            }                                                                 \
        }                                                                     \
        __builtin_amdgcn_s_setprio(0);                                        \
        _Pragma("unroll") for (int g = 0; g < 2; ++g)                         \
            _Pragma("unroll") for (int nt = 0; nt < 4; ++nt)                  \
                _Pragma("unroll") for (int r = 0; r < 4; ++r)                 \
                    sc[g][nt][r] = __builtin_amdgcn_exp2f(sc[g][nt][r]);      \
        short8 ap[2][2];                                                      \
        _Pragma("unroll") for (int g = 0; g < 2; ++g)                         \
            _Pragma("unroll") for (int hf = 0; hf < 2; ++hf) {                \
                int4v wv;                                                     \
                wv.x = cvtpk_bf16(sc[g][2 * hf + 0][0], sc[g][2 * hf + 0][1]); \
                wv.y = cvtpk_bf16(sc[g][2 * hf + 0][2], sc[g][2 * hf + 0][3]); \
                wv.z = cvtpk_bf16(sc[g][2 * hf + 1][0], sc[g][2 * hf + 1][1]); \
                wv.w = cvtpk_bf16(sc[g][2 * hf + 1][2], sc[g][2 * hf + 1][3]); \
                ap[g][hf] = i4_to_s8(wv);                                     \
            }                                                                 \
        __builtin_amdgcn_s_setprio(1);                                        \
        _Pragma("unroll") for (int g = 0; g < 2; ++g) {                       \
            lacc[g] = __builtin_amdgcn_mfma_f32_16x16x32_bf16(ap[g][0], ones, lacc[g], 0, 0, 0); \
            lacc[g] = __builtin_amdgcn_mfma_f32_16x16x32_bf16(ap[g][1], ones, lacc[g], 0, 0, 0); \
        }                                                                     \
        const int rsw = m & 7, hb = (quad & 1) * 4;                           \
        _Pragma("unroll") for (int dt = 0; dt < 4; ++dt) {                    \
            const short* vb = (Vbuf) + (dt * 16 + m) * 64;                    \
            short4v l0 = *(const short4v*)&vb[((((quad >> 1) + 0) ^ rsw) << 3) + hb]; \
            short4v h0 = *(const short4v*)&vb[((((quad >> 1) + 2) ^ rsw) << 3) + hb]; \
            short4v l1 = *(const short4v*)&vb[((((quad >> 1) + 4) ^ rsw) << 3) + hb]; \
            short4v h1 = *(const short4v*)&vb[((((quad >> 1) + 6) ^ rsw) << 3) + hb]; \
            short8 b0 = __builtin_shufflevector(l0, h0, 0, 1, 2, 3, 4, 5, 6, 7); \
            short8 b1 = __builtin_shufflevector(l1, h1, 0, 1, 2, 3, 4, 5, 6, 7); \
            _Pragma("unroll") for (int g = 0; g < 2; ++g) {                   \
                O[g][dt] = __builtin_amdgcn_mfma_f32_16x16x32_bf16(ap[g][0], b0, O[g][dt], 0, 0, 0); \
                O[g][dt] = __builtin_amdgcn_mfma_f32_16x16x32_bf16(ap[g][1], b1, O[g][dt], 0, 0, 0); \
            }                                                                 \
        }                                                                     \
        __builtin_amdgcn_s_setprio(0);                                        \
    } while (0)

__global__ __launch_bounds__(256)
void attn_mfma(const short* __restrict__ Q,
               const short* __restrict__ K,
               const short* __restrict__ Vt,
               short* __restrict__ out) {
    __shared__ short K0l[64 * 64];       // 8192 B each; double-buffered
    __shared__ short K1l[64 * 64];
    __shared__ short V0l[64 * 64];
    __shared__ short V1l[64 * 64];

    const int tid  = threadIdx.x;
    const int w    = tid >> 6;
    const int l    = tid & 63;
    const int m    = l & 15;
    const int quad = l >> 4;

    const int flat = blockIdx.x + 8 * blockIdx.y + 96 * blockIdx.z;  // 0..767
    const int id   = (flat & 7) * 96 + (flat >> 3);
    const int qt   = id & 7;
    const int bh   = id >> 3;            // 0..95
    const int b    = bh / HH;
    const int h    = bh % HH;
    const int q0   = qt * 128;

    const short* Qg = Q  + (long)bh * SS * DD;
    const short* Kg = K  + (long)bh * SS * DD;
    const short* Vg = Vt + (long)bh * DD * SS;

    // Q B-fragments (swapped QK): lane m = q, regs = d — same addressing
    short8 aq[2][2];
#pragma unroll
    for (int g = 0; g < 2; ++g) {
        const int row = q0 + w * 32 + g * 16 + m;
        aq[g][0] = *(const short8*)(Qg + (long)row * DD + quad * 8);
        aq[g][1] = *(const short8*)(Qg + (long)row * DD + 32 + quad * 8);
    }

    short8 ones;
#pragma unroll
    for (int i = 0; i < 8; ++i) ones[i] = (short)0x3F80;

    f32x4 O[2][4], lacc[2];
#pragma unroll
    for (int g = 0; g < 2; ++g) {
        lacc[g] = (f32x4){0.f, 0.f, 0.f, 0.f};
#pragma unroll
        for (int dt = 0; dt < 4; ++dt) O[g][dt] = (f32x4){0.f, 0.f, 0.f, 0.f};
    }

    ATTN_STAGE(K0l, V0l, 0);
    __syncthreads();

#pragma unroll 1
    for (int kt2 = 0; kt2 < 8; ++kt2) {
        const int k0 = kt2 * 128;
        ATTN_STAGE(K1l, V1l, k0 + 64);
        ATTN_COMPUTE(K0l, V0l);
        __syncthreads();
        if (kt2 < 7) ATTN_STAGE(K0l, V0l, k0 + 128);
        ATTN_COMPUTE(K1l, V1l);
        __syncthreads();
    }

#pragma unroll
    for (int g = 0; g < 2; ++g)
#pragma unroll
        for (int r = 0; r < 4; ++r) {
            const float inv = 1.0f / lacc[g][r];
            const int qo = q0 + w * 32 + g * 16 + quad * 4 + r;
            short* orow = out + ((long)(b * SS + qo)) * EE + h * DD;
#pragma unroll
            for (int dt = 0; dt < 4; ++dt)
                orow[dt * 16 + m] = f2bf(O[g][dt][r] * inv);
        }
}

// ---------------------------------------------------------------------------
extern "C" void kernel_launch(void* const* d_in, const int* in_sizes, int n_in,
                              void* d_out, int out_size, void* d_ws, size_t ws_size,
                              hipStream_t stream) {
    const float* X  = (const float*)d_in[0];
    const float* Wq = (const float*)d_in[1];
    const float* bq = (const float*)d_in[2];
    const float* Wk = (const float*)d_in[3];
    const float* bk = (const float*)d_in[4];
    const float* Wv = (const float*)d_in[5];
    const float* bv = (const float*)d_in[6];
    const float* Wo = (const float*)d_in[7];
    const float* bo = (const float*)d_in[8];

    const long SEG = (long)BB * HH * SS * DD;     // 6,291,456 elements
    const long WSEG = (long)EE * EE;              // 589,824
    short* Xb = (short*)d_ws;                     // [M][E] bf16
    short* Wt = Xb + SEG;                         // [4][E][E] bf16, N-major
    short* Qb = Wt + 4 * WSEG;                    // [B,H,S,D] bf16, pre-scaled
    short* Kb = Qb + SEG;                         // [B,H,S,D] bf16
    short* Vb = Kb + SEG;                         // [B,H,D,S] bf16
    short* Cb = Vb + SEG;                         // [M][E] bf16 concat

    prep<<<dim3(6720), 256, 0, stream>>>(X, Xb, Wq, Wk, Wv, Wo, Wt);

    gemm_qkv<<<dim3(18, 32), 512, 0, stream>>>(Xb, Wt, bq, bk, bv, Qb, Kb, Vb);

    attn_mfma<<<dim3(SS / 128, HH, BB), 256, 0, stream>>>(Qb, Kb, Vb, Cb);

    gemm_proj<<<dim3(6, 64), 256, 0, stream>>>(Cb, Wt + 3 * WSEG, bo,
                                               (float*)d_out);
}

// Round 13
// 192.408 us; speedup vs baseline: 1.8266x; 1.0122x over previous
//
#include <hip/hip_runtime.h>
#include <math.h>

#define BB 8
#define SS 1024
#define EE 768
#define HH 12
#define DD 64
#define MM (BB*SS)   // 8192

typedef __attribute__((ext_vector_type(8))) short short8;   // 8 bf16 = 4 VGPRs
typedef __attribute__((ext_vector_type(4))) short short4v;  // 8 B
typedef __attribute__((ext_vector_type(4))) float f32x4;
typedef __attribute__((ext_vector_type(4))) int int4v;

// round-to-nearest-even fp32 -> bf16 bits (finite inputs only)
static __device__ __forceinline__ short f2bf(float x) {
    unsigned u = __float_as_uint(x);
    u += 0x7fffu + ((u >> 16) & 1u);
    return (short)(u >> 16);
}
// packed fp32x2 -> bf16x2 (D.l = bf16(lo), D.h = bf16(hi))
static __device__ __forceinline__ int cvtpk_bf16(float lo, float hi) {
    int r;
    asm("v_cvt_pk_bf16_f32 %0, %1, %2" : "=v"(r) : "v"(lo), "v"(hi));
    return r;
}
static __device__ __forceinline__ short8 i4_to_s8(int4v v) {
    union { int4v i; short8 s; } u; u.i = v; return u.s;
}

// async global->LDS, 16B per lane; LDS dest = wave-uniform base + lane*16
static __device__ __forceinline__ void gload_lds16(const void* g, void* l) {
    __builtin_amdgcn_global_load_lds((__attribute__((address_space(1))) void*)g,
                                     (__attribute__((address_space(3))) void*)l,
                                     16, 0, 0);
}

#define BAR __builtin_amdgcn_s_barrier()
#define VMW(n) asm volatile("s_waitcnt vmcnt(" #n ")" ::: "memory")

// ---------------------------------------------------------------------------
// prep: fused cast_x (blocks 0..6143) + wcast_t (blocks 6144..6719).
// ---------------------------------------------------------------------------
__global__ __launch_bounds__(256)
void prep(const float* __restrict__ X, short* __restrict__ Xb,
          const float* __restrict__ W0, const float* __restrict__ W1,
          const float* __restrict__ W2, const float* __restrict__ W3,
          short* __restrict__ Wt) {
    const int tid = threadIdx.x;
    if (blockIdx.x < 6144) {
        const long i = ((long)blockIdx.x * 256 + tid) * 4;
        float4 v = *(const float4*)&X[i];
        short4v o;
        o.x = f2bf(v.x); o.y = f2bf(v.y); o.z = f2bf(v.z); o.w = f2bf(v.w);
        *(short4v*)&Xb[i] = o;
        return;
    }
    __shared__ short T[64][72];
    const int id = blockIdx.x - 6144;            // 0..575
    const int z  = id / 144;
    const int r2 = id % 144;
    const int i0 = (r2 / 12) * 64;
    const int j0 = (r2 % 12) * 64;
    const float* sp = (z == 0) ? W0 : (z == 1) ? W1 : (z == 2) ? W2 : W3;
    short* dp = Wt + (long)z * EE * EE;
#pragma unroll
    for (int rep = 0; rep < 4; ++rep) {
        const int r = (tid >> 4) + rep * 16;
        const int c = (tid & 15) * 4;
        float4 v = *(const float4*)&sp[(long)(i0 + r) * EE + j0 + c];
        T[c + 0][r] = f2bf(v.x);
        T[c + 1][r] = f2bf(v.y);
        T[c + 2][r] = f2bf(v.z);
        T[c + 3][r] = f2bf(v.w);
    }
    __syncthreads();
#pragma unroll
    for (int rep = 0; rep < 4; ++rep) {
        const int rr = (tid >> 4) + rep * 16;
        const int cc = (tid & 15) * 4;
        short4v o;
        o.x = T[rr][cc + 0]; o.y = T[rr][cc + 1];
        o.z = T[rr][cc + 2]; o.w = T[rr][cc + 3];
        *(short4v*)&dp[(long)(j0 + rr) * EE + i0 + cc] = o;
    }
}

// Q pre-scale: 1/sqrt(D) * log2(e)  (exp done as 2^x in attention)
#define QSCALE 0.1803368801111204f

// ---------------------------------------------------------------------------
// Shared 4-phase counted-vmcnt GEMM schedule (round-6 verified, 48.0 us in
// qkv): 256x128 tile, BK=64, 512 thr / 8 waves (2M x 4N), per-wave C =
// 128x32 = acc[8][2]. LDS 96 KiB dual-buffered A (Ae/Ao) + B (Be/Bo),
// VMW(6) per phase = 6 loads always in flight.
// Occupancy-reduction variants (80 KiB: 51.7; 64 KiB ring: 61.6) and the
// 192-block grid-barrier mega-fusion (283 us) all lost — prefetch depth +
// independent multi-block TLP is what this workload pays for.
// ---------------------------------------------------------------------------
#define STG1(Ld, Gbase, gr0, k0)                                              \
    do {                                                                      \
        const int r_ = tid >> 3;                                              \
        const int cs_ = ((tid & 7) ^ (r_ & 7)) << 3;                          \
        gload_lds16(&(Gbase)[(long)((gr0) + r_) * EE + (k0) + cs_],           \
                    (Ld) + w * 512);                                          \
    } while (0)

#define QKV_RDA(Ld, mb)                                                       \
    _Pragma("unroll") for (int t = 0; t < 4; ++t)                             \
        _Pragma("unroll") for (int ks = 0; ks < 2; ++ks)                      \
            af[t][ks] = *(const short8*)&(Ld)[(wr * 128 + ((mb) + t) * 16 + m) * 64 + \
                                              (((ks * 4 + quad) ^ (m & 7)) << 3)];

#define QKV_RDB(Ld)                                                           \
    _Pragma("unroll") for (int t = 0; t < 2; ++t)                             \
        _Pragma("unroll") for (int ks = 0; ks < 2; ++ks)                      \
            bf[t][ks] = *(const short8*)&(Ld)[(wc * 32 + t * 16 + m) * 64 +   \
                                              (((ks * 4 + quad) ^ (m & 7)) << 3)];

#define QKV_MF(mb)                                                            \
    __builtin_amdgcn_s_setprio(1);                                            \
    _Pragma("unroll") for (int mq = 0; mq < 4; ++mq)                          \
        _Pragma("unroll") for (int nq = 0; nq < 2; ++nq)                      \
            _Pragma("unroll") for (int ks = 0; ks < 2; ++ks)                  \
                acc[(mb) + mq][nq] = __builtin_amdgcn_mfma_f32_16x16x32_bf16( \
                    af[mq][ks], bf[nq][ks], acc[(mb) + mq][nq], 0, 0, 0);     \
    __builtin_amdgcn_s_setprio(0);

// K-loop body shared by gemm_qkv and gemm_proj (identical ledger)
#define GEMM4P_LOOP(Abase, Bbase, row0, col0)                                 \
    STG1(Ae + 0,     Abase, (row0) + 0,    0);                                \
    STG1(Ae + 8192,  Abase, (row0) + 128,  0);                                \
    STG1(Be + 0,     Bbase, (col0) + 0,    0);                                \
    STG1(Be + 4096,  Bbase, (col0) + 64,   0);                                \
    STG1(Ae + 4096,  Abase, (row0) + 64,   0);                                \
    STG1(Ae + 12288, Abase, (row0) + 192,  0);                                \
    STG1(Bo + 0,     Bbase, (col0) + 0,    64);                               \
    STG1(Bo + 4096,  Bbase, (col0) + 64,   64);                               \
    STG1(Ao + 0,     Abase, (row0) + 0,    64);                               \
    STG1(Ao + 8192,  Abase, (row0) + 128,  64);                               \
    VMW(6);                                                                   \
    BAR;                                                                      \
    _Pragma("unroll 1")                                                       \
    for (int it = 0; it < 6; ++it) {                                          \
        const int kO1 = (2 * it + 1) * 64;                                    \
        const int t2 = 2 * it + 2, t3 = 2 * it + 3;                           \
        const int kE2 = (t2 < 12 ? t2 : 11) * 64;                             \
        const int kO3 = (t3 < 12 ? t3 : 11) * 64;                             \
        short8 af[4][2], bf[2][2];                                            \
        QKV_RDA(Ae, 0);                                                       \
        QKV_RDB(Be);                                                          \
        STG1(Ao + 4096,  Abase, (row0) + 64,  kO1);                           \
        STG1(Ao + 12288, Abase, (row0) + 192, kO1);                           \
        BAR;                                                                  \
        QKV_MF(0);                                                            \
        VMW(6);                                                               \
        BAR;                                                                  \
        QKV_RDA(Ae, 4);                                                       \
        STG1(Be + 0,     Bbase, (col0) + 0,   kE2);                           \
        STG1(Be + 4096,  Bbase, (col0) + 64,  kE2);                           \
        STG1(Ae + 0,     Abase, (row0) + 0,   kE2);                           \
        STG1(Ae + 8192,  Abase, (row0) + 128, kE2);                           \
        BAR;                                                                  \
        QKV_MF(4);                                                            \
        VMW(6);                                                               \
        BAR;                                                                  \
        QKV_RDA(Ao, 0);                                                       \
        QKV_RDB(Bo);                                                          \
        STG1(Ae + 4096,  Abase, (row0) + 64,  kE2);                           \
        STG1(Ae + 12288, Abase, (row0) + 192, kE2);                           \
        BAR;                                                                  \
        QKV_MF(0);                                                            \
        VMW(6);                                                               \
        BAR;                                                                  \
        QKV_RDA(Ao, 4);                                                       \
        STG1(Bo + 0,     Bbase, (col0) + 0,   kO3);                           \
        STG1(Bo + 4096,  Bbase, (col0) + 64,  kO3);                           \
        STG1(Ao + 0,     Abase, (row0) + 0,   kO3);                           \
        STG1(Ao + 8192,  Abase, (row0) + 128, kO3);                           \
        BAR;                                                                  \
        QKV_MF(4);                                                            \
        VMW(6);                                                               \
        BAR;                                                                  \
    }

__global__ __launch_bounds__(512, 2)
void gemm_qkv(const short* __restrict__ Xb, const short* __restrict__ Wt,
              const float* __restrict__ bq, const float* __restrict__ bk,
              const float* __restrict__ bv,
              short* __restrict__ Qb, short* __restrict__ Kb,
              short* __restrict__ Vb) {
    __shared__ short SMEM[49152];            // 96 KiB
    short* const Ae = SMEM;                  // 256x64 bf16 even-tile A
    short* const Ao = SMEM + 16384;          // odd-tile A
    short* const Be = SMEM + 32768;          // 128x64 bf16 even-tile B
    short* const Bo = SMEM + 40960;          // odd-tile B

    const int tid = threadIdx.x;
    const int w = tid >> 6;
    const int m = tid & 15, quad = (tid & 63) >> 4;
    const int wr = w >> 2, wc = w & 3;       // 2M x 4N wave grid

    const int flat = blockIdx.x + 18 * blockIdx.y;      // 0..575
    const int id   = (flat & 7) * 72 + (flat >> 3);
    const int lcl  = id % 72;
    const int rt   = (id / 72) * 4 + (lcl & 3);         // 0..31
    const int ct   = lcl >> 2;                          // 0..17
    const int row0 = rt * 256;
    const int wsel = ct / 6;
    const int col0w = (ct % 6) * 128;
    const short* Wsel = Wt + (long)wsel * EE * EE;
    const float* bias = (wsel == 0) ? bq : (wsel == 1) ? bk : bv;

    f32x4 acc[8][2];
#pragma unroll
    for (int i = 0; i < 8; ++i)
#pragma unroll
        for (int j = 0; j < 2; ++j) acc[i][j] = (f32x4){0.f, 0.f, 0.f, 0.f};

    GEMM4P_LOOP(Xb, Wsel, row0, col0w)

    // ---- epilogue ----
    VMW(0);
    __syncthreads();
    const int b = row0 >> 10, s0 = row0 & 1023;
    short* EP = SMEM;

    if (wsel < 2) {
        // Q/K -> [B,H,S,D]; EP as [256][136]
        const float scale = (wsel == 0) ? QSCALE : 1.0f;
        short* QK = (wsel == 0) ? Qb : Kb;
#pragma unroll
        for (int nt = 0; nt < 2; ++nt) {
            const float bvv = bias[col0w + wc * 32 + nt * 16 + m];
#pragma unroll
            for (int mt = 0; mt < 8; ++mt)
#pragma unroll
                for (int r = 0; r < 4; ++r)
                    EP[(wr * 128 + mt * 16 + quad * 4 + r) * 136 + wc * 32 + nt * 16 + m] =
                        f2bf((acc[mt][nt][r] + bvv) * scale);
        }
        __syncthreads();
#pragma unroll
        for (int rep = 0; rep < 8; ++rep) {
            const int chunk = tid + rep * 512;      // 0..4095
            const int row = chunk >> 4;             // 0..255
            const int cc = (chunk & 15) * 8;        // 0..120
            const int colg = col0w + cc;
            const int h = colg >> 6, d = colg & 63;
            short8 v = *(const short8*)&EP[row * 136 + cc];
            *(short8*)&QK[((long)(b * HH + h) * SS + s0 + row) * DD + d] = v;
        }
    } else {
        // V -> [B,H,D,S]; EP transposed as [128][264]
#pragma unroll
        for (int nt = 0; nt < 2; ++nt) {
            const float bvv = bias[col0w + wc * 32 + nt * 16 + m];
#pragma unroll
            for (int mt = 0; mt < 8; ++mt) {
                short4v o;
                o.x = f2bf(acc[mt][nt][0] + bvv);
                o.y = f2bf(acc[mt][nt][1] + bvv);
                o.z = f2bf(acc[mt][nt][2] + bvv);
                o.w = f2bf(acc[mt][nt][3] + bvv);
                *(short4v*)&EP[(wc * 32 + nt * 16 + m) * 264 + wr * 128 + mt * 16 + quad * 4] = o;
            }
        }
        __syncthreads();
#pragma unroll
        for (int rep = 0; rep < 8; ++rep) {
            const int chunk = tid + rep * 512;      // 0..4095
            const int col = chunk >> 5;             // 0..127
            const int sc8 = (chunk & 31) * 8;       // 0..248
            const int colg = col0w + col;
            const int h = colg >> 6, d = colg & 63;
            short8 v = *(const short8*)&EP[col * 264 + sc8];
            *(short8*)&Vb[((long)(b * HH + h) * DD + d) * SS + s0 + sc8] = v;
        }
    }
}

// ---------------------------------------------------------------------------
// Output projection — round-13: same 4-phase 256x128 schedule as qkv.
// Grid 32x6 = 192 blocks = sub-one-round (zero tail, vs old 384-block m97
// structure's 1.5-round 75% tail). Epilogue simplifies: fp32 direct store
// from acc + bias, no LDS round-trip. XCD chunk = 24 tiles = 4 row-panels
// x all 6 cols (A 1.5 MB + B 1.1 MB, L2-fit).
// ---------------------------------------------------------------------------
__global__ __launch_bounds__(512, 2)
void gemm_proj(const short* __restrict__ Cb, const short* __restrict__ WoT,
               const float* __restrict__ bo, float* __restrict__ out) {
    __shared__ short SMEM[49152];            // 96 KiB
    short* const Ae = SMEM;
    short* const Ao = SMEM + 16384;
    short* const Be = SMEM + 32768;
    short* const Bo = SMEM + 40960;

    const int tid = threadIdx.x;
    const int w = tid >> 6;
    const int m = tid & 15, quad = (tid & 63) >> 4;
    const int wr = w >> 2, wc = w & 3;

    const int flat = blockIdx.x + 6 * blockIdx.y;       // 0..191
    const int id   = (flat & 7) * 24 + (flat >> 3);
    const int lcl  = id % 24;
    const int rt   = (id / 24) * 4 + (lcl & 3);         // 0..31
    const int ct   = lcl >> 2;                          // 0..5
    const int row0 = rt * 256;
    const int col0 = ct * 128;

    f32x4 acc[8][2];
#pragma unroll
    for (int i = 0; i < 8; ++i)
#pragma unroll
        for (int j = 0; j < 2; ++j) acc[i][j] = (f32x4){0.f, 0.f, 0.f, 0.f};

    GEMM4P_LOOP(Cb, WoT, row0, col0)

    // ---- epilogue: fp32 direct store + bias (no LDS round-trip) ----
    VMW(0);
    __syncthreads();
#pragma unroll
    for (int nt = 0; nt < 2; ++nt) {
        const int colg = col0 + wc * 32 + nt * 16 + m;
        const float bvv = bo[colg];
#pragma unroll
        for (int mt = 0; mt < 8; ++mt)
#pragma unroll
            for (int r = 0; r < 4; ++r) {
                const int srow = row0 + wr * 128 + mt * 16 + quad * 4 + r;
                out[(long)srow * EE + colg] = acc[mt][nt][r] + bvv;
            }
    }
}

// ---------------------------------------------------------------------------
// Flash attention, bf16 MFMA 16x16x32. SWAPPED QK^T + in-register P.
// (round-6 version, verified)
// ---------------------------------------------------------------------------
#define ATTN_STAGE(Kdst, Vdst, k0)                                            \
    do {                                                                      \
        _Pragma("unroll") for (int i = 0; i < 2; ++i) {                       \
            const int chunk = w * 128 + i * 64 + l;                           \
            const int r = chunk >> 3;                                         \
            const int cs = ((chunk & 7) ^ (r & 7)) << 3;                      \
            gload_lds16(&Kg[(long)((k0) + r) * DD + cs],                      \
                        (Kdst) + (w * 128 + i * 64) * 8);                     \
            gload_lds16(&Vg[(long)r * SS + (k0) + cs],                        \
                        (Vdst) + (w * 128 + i * 64) * 8);                     \
        }                                                                     \
    } while (0)

#define ATTN_COMPUTE(Kbuf, Vbuf)                                              \
    do {                                                                      \
        f32x4 sc[2][4];                                                       \
        __builtin_amdgcn_s_setprio(1);                                        \
        _Pragma("unroll") for (int nt = 0; nt < 4; ++nt) {                    \
            const short* kb = (Kbuf) + (nt * 16 + m) * 64;                    \
            short8 a0 = *(const short8*)&kb[(quad ^ (m & 7)) << 3];           \
            short8 a1 = *(const short8*)&kb[((4 + quad) ^ (m & 7)) << 3];     \
            _Pragma("unroll") for (int g = 0; g < 2; ++g) {                   \
                f32x4 a = (f32x4){0.f, 0.f, 0.f, 0.f};                        \
                a = __builtin_amdgcn_mfma_f32_16x16x32_bf16(a0, aq[g][0], a, 0, 0, 0); \
                a = __builtin_amdgcn_mfma_f32_16x16x32_bf16(a1, aq[g][1], a, 0, 0, 0); \
                sc[g][nt] = a;                                                \
            }                                                                 \
        }                                                                     \
        __builtin_amdgcn_s_setprio(0);                                        \
        _Pragma("unroll") for (int g = 0; g < 2; ++g)                         \
            _Pragma("unroll") for (int nt = 0; nt < 4; ++nt)                  \
                _Pragma("unroll") for (int r = 0; r < 4; ++r)                 \
                    sc[g][nt][r] = __builtin_amdgcn_exp2f(sc[g][nt][r]);      \
        short8 ap[2][2];                                                      \
        _Pragma("unroll") for (int g = 0; g < 2; ++g)                         \
            _Pragma("unroll") for (int hf = 0; hf < 2; ++hf) {                \
                int4v wv;                                                     \
                wv.x = cvtpk_bf16(sc[g][2 * hf + 0][0], sc[g][2 * hf + 0][1]); \
                wv.y = cvtpk_bf16(sc[g][2 * hf + 0][2], sc[g][2 * hf + 0][3]); \
                wv.z = cvtpk_bf16(sc[g][2 * hf + 1][0], sc[g][2 * hf + 1][1]); \
                wv.w = cvtpk_bf16(sc[g][2 * hf + 1][2], sc[g][2 * hf + 1][3]); \
                ap[g][hf] = i4_to_s8(wv);                                     \
            }                                                                 \
        __builtin_amdgcn_s_setprio(1);                                        \
        _Pragma("unroll") for (int g = 0; g < 2; ++g) {                       \
            lacc[g] = __builtin_amdgcn_mfma_f32_16x16x32_bf16(ap[g][0], ones, lacc[g], 0, 0, 0); \
            lacc[g] = __builtin_amdgcn_mfma_f32_16x16x32_bf16(ap[g][1], ones, lacc[g], 0, 0, 0); \
        }                                                                     \
        const int rsw = m & 7, hb = (quad & 1) * 4;                           \
        _Pragma("unroll") for (int dt = 0; dt < 4; ++dt) {                    \
            const short* vb = (Vbuf) + (dt * 16 + m) * 64;                    \
            short4v l0 = *(const short4v*)&vb[((((quad >> 1) + 0) ^ rsw) << 3) + hb]; \
            short4v h0 = *(const short4v*)&vb[((((quad >> 1) + 2) ^ rsw) << 3) + hb]; \
            short4v l1 = *(const short4v*)&vb[((((quad >> 1) + 4) ^ rsw) << 3) + hb]; \
            short4v h1 = *(const short4v*)&vb[((((quad >> 1) + 6) ^ rsw) << 3) + hb]; \
            short8 b0 = __builtin_shufflevector(l0, h0, 0, 1, 2, 3, 4, 5, 6, 7); \
            short8 b1 = __builtin_shufflevector(l1, h1, 0, 1, 2, 3, 4, 5, 6, 7); \
            _Pragma("unroll") for (int g = 0; g < 2; ++g) {                   \
                O[g][dt] = __builtin_amdgcn_mfma_f32_16x16x32_bf16(ap[g][0], b0, O[g][dt], 0, 0, 0); \
                O[g][dt] = __builtin_amdgcn_mfma_f32_16x16x32_bf16(ap[g][1], b1, O[g][dt], 0, 0, 0); \
            }                                                                 \
        }                                                                     \
        __builtin_amdgcn_s_setprio(0);                                        \
    } while (0)

__global__ __launch_bounds__(256)
void attn_mfma(const short* __restrict__ Q,
               const short* __restrict__ K,
               const short* __restrict__ Vt,
               short* __restrict__ out) {
    __shared__ short K0l[64 * 64];       // 8192 B each; double-buffered
    __shared__ short K1l[64 * 64];
    __shared__ short V0l[64 * 64];
    __shared__ short V1l[64 * 64];

    const int tid  = threadIdx.x;
    const int w    = tid >> 6;
    const int l    = tid & 63;
    const int m    = l & 15;
    const int quad = l >> 4;

    const int flat = blockIdx.x + 8 * blockIdx.y + 96 * blockIdx.z;  // 0..767
    const int id   = (flat & 7) * 96 + (flat >> 3);
    const int qt   = id & 7;
    const int bh   = id >> 3;            // 0..95
    const int b    = bh / HH;
    const int h    = bh % HH;
    const int q0   = qt * 128;

    const short* Qg = Q  + (long)bh * SS * DD;
    const short* Kg = K  + (long)bh * SS * DD;
    const short* Vg = Vt + (long)bh * DD * SS;

    // Q B-fragments (swapped QK): lane m = q, regs = d — same addressing
    short8 aq[2][2];
#pragma unroll
    for (int g = 0; g < 2; ++g) {
        const int row = q0 + w * 32 + g * 16 + m;
        aq[g][0] = *(const short8*)(Qg + (long)row * DD + quad * 8);
        aq[g][1] = *(const short8*)(Qg + (long)row * DD + 32 + quad * 8);
    }

    short8 ones;
#pragma unroll
    for (int i = 0; i < 8; ++i) ones[i] = (short)0x3F80;

    f32x4 O[2][4], lacc[2];
#pragma unroll
    for (int g = 0; g < 2; ++g) {
        lacc[g] = (f32x4){0.f, 0.f, 0.f, 0.f};
#pragma unroll
        for (int dt = 0; dt < 4; ++dt) O[g][dt] = (f32x4){0.f, 0.f, 0.f, 0.f};
    }

    ATTN_STAGE(K0l, V0l, 0);
    __syncthreads();

#pragma unroll 1
    for (int kt2 = 0; kt2 < 8; ++kt2) {
        const int k0 = kt2 * 128;
        ATTN_STAGE(K1l, V1l, k0 + 64);
        ATTN_COMPUTE(K0l, V0l);
        __syncthreads();
        if (kt2 < 7) ATTN_STAGE(K0l, V0l, k0 + 128);
        ATTN_COMPUTE(K1l, V1l);
        __syncthreads();
    }

#pragma unroll
    for (int g = 0; g < 2; ++g)
#pragma unroll
        for (int r = 0; r < 4; ++r) {
            const float inv = 1.0f / lacc[g][r];
            const int qo = q0 + w * 32 + g * 16 + quad * 4 + r;
            short* orow = out + ((long)(b * SS + qo)) * EE + h * DD;
#pragma unroll
            for (int dt = 0; dt < 4; ++dt)
                orow[dt * 16 + m] = f2bf(O[g][dt][r] * inv);
        }
}

// ---------------------------------------------------------------------------
extern "C" void kernel_launch(void* const* d_in, const int* in_sizes, int n_in,
                              void* d_out, int out_size, void* d_ws, size_t ws_size,
                              hipStream_t stream) {
    const float* X  = (const float*)d_in[0];
    const float* Wq = (const float*)d_in[1];
    const float* bq = (const float*)d_in[2];
    const float* Wk = (const float*)d_in[3];
    const float* bk = (const float*)d_in[4];
    const float* Wv = (const float*)d_in[5];
    const float* bv = (const float*)d_in[6];
    const float* Wo = (const float*)d_in[7];
    const float* bo = (const float*)d_in[8];

    const long SEG = (long)BB * HH * SS * DD;     // 6,291,456 elements
    const long WSEG = (long)EE * EE;              // 589,824
    short* Xb = (short*)d_ws;                     // [M][E] bf16
    short* Wt = Xb + SEG;                         // [4][E][E] bf16, N-major
    short* Qb = Wt + 4 * WSEG;                    // [B,H,S,D] bf16, pre-scaled
    short* Kb = Qb + SEG;                         // [B,H,S,D] bf16
    short* Vb = Kb + SEG;                         // [B,H,D,S] bf16
    short* Cb = Vb + SEG;                         // [M][E] bf16 concat

    prep<<<dim3(6720), 256, 0, stream>>>(X, Xb, Wq, Wk, Wv, Wo, Wt);

    gemm_qkv<<<dim3(18, 32), 512, 0, stream>>>(Xb, Wt, bq, bk, bv, Qb, Kb, Vb);

    attn_mfma<<<dim3(SS / 128, HH, BB), 256, 0, stream>>>(Qb, Kb, Vb, Cb);

    gemm_proj<<<dim3(6, 32), 512, 0, stream>>>(Cb, Wt + 3 * WSEG, bo,
                                               (float*)d_out);
}